// Round 1
// 261.226 us; speedup vs baseline: 1.0166x; 1.0166x over previous
//
#include <hip/hip_runtime.h>

// Problem: adjacency_full[i, neighbor_indices[i,k]] = adjacency_values[i,k]
// over a zeroed [N,N] fp32 matrix. N=8192, K=64.
// Write-BW bound: 256 MiB of output writes vs 6 MiB of input reads.
//
// Structure (v2): one block per row.
//   phase 0: threads 0..63 prefetch this row's (idx, val) pairs into registers
//   phase 1: all 256 threads stream zeros straight from registers to the row
//            (float4, fully coalesced, no LDS round-trip)
//   __syncthreads(): compiler emits s_waitcnt vmcnt(0) before s_barrier, so
//            every zero store has reached the (same-XCD) L2 before any thread
//            proceeds -> write-after-write order to the same addresses is safe
//   phase 2: threads 0..63 patch their value with a direct 4 B store; the
//            target lines were just written by this block and are L2-resident,
//            so each output line is written back to HBM exactly once.
//
// No LDS at all -> 8 blocks/CU (wave-limited) instead of 5 (LDS-limited),
// no ds_read->store dependency in the streaming loop, one barrier instead of two.

constexpr int N_PATCH = 8192;
constexpr int K_NB = 64;
constexpr int BLOCK = 256;
constexpr int VEC_ITERS = N_PATCH / 4 / BLOCK;  // 8 float4 per thread

__global__ __launch_bounds__(BLOCK)
void scatter_rows_kernel(const float* __restrict__ vals,
                         const int* __restrict__ idx,
                         float* __restrict__ out) {
    const int r = blockIdx.x;
    const int t = threadIdx.x;

    // Phase 0: prefetch scatter pairs early so HBM load latency hides under
    // the zero-store stream below.
    int c = 0;
    float v = 0.f;
    if (t < K_NB) {
        const int base = r * K_NB + t;
        c = idx[base];
        v = vals[base];
    }
    // Pin the loads before the store stream (prevents the compiler sinking
    // them past the barrier where they'd serialize with the scatter).
    asm volatile("" : "+v"(c), "+v"(v));

    // Phase 1: stream zeros directly to global, fully coalesced float4 stores.
    float4* outv = reinterpret_cast<float4*>(out + (size_t)r * N_PATCH);
    const float4 z = make_float4(0.f, 0.f, 0.f, 0.f);
#pragma unroll
    for (int i = 0; i < VEC_ITERS; ++i)
        outv[t + i * BLOCK] = z;

    // Drain zero stores to L2 (vmcnt(0) precedes s_barrier), then patch.
    __syncthreads();

    // Phase 2: scattered 4 B stores into just-written, L2-resident lines.
    if (t < K_NB)
        out[(size_t)r * N_PATCH + c] = v;
}

extern "C" void kernel_launch(void* const* d_in, const int* in_sizes, int n_in,
                              void* d_out, int out_size, void* d_ws, size_t ws_size,
                              hipStream_t stream) {
    const float* vals = (const float*)d_in[0];   // adjacency_values [N,K] fp32
    const int* idx = (const int*)d_in[1];        // neighbor_indices [N,K] int32
    float* out = (float*)d_out;                  // [N,N] fp32

    scatter_rows_kernel<<<N_PATCH, BLOCK, 0, stream>>>(vals, idx, out);
}